// Round 1
// baseline (1104.663 us; speedup 1.0000x reference)
//
#include <hip/hip_runtime.h>

// ThreePhaseTerm: sparse chemistry RHS assembly on MI355X.
// Structure:
//   K1 scalars_kernel  (grid=B):   y_surf/y_mant sums + gain/loss masked edge
//                                  reductions -> k_s2m[b], k_m2s[b] in ws
//   K2 final_kernel    (grid=B*NC): LDS-accumulated scatter over E1+E2 edges,
//                                  Arrhenius coeff computed on the fly
//                                  (alpha/beta/gamma tables are L2-resident),
//                                  global atomicAdd into zeroed d_out.

constexpr int B_    = 256;
constexpr int S_    = 800;
constexpr int NR_   = 80000;
constexpr int E1_   = 60000;
constexpr int E2_   = 180000;
constexpr int E1G_  = 15000;
constexpr int E2G_  = 45000;
constexpr int E1L_  = 15000;
constexpr int E2L_  = 45000;
constexpr int NSMT_ = 600;
constexpr float LOG2E_ = 1.4426950408889634f;
constexpr float EPS_   = 1e-30f;
constexpr int   NCHUNK = 8;          // blocks per batch in final kernel
constexpr int   TPB    = 256;

// Arrhenius coefficient, fused into a single exp2:
// alpha * (T/300)^beta * exp(-gamma/T) = alpha * exp2(beta*lt2 + gamma*nivt)
__device__ __forceinline__ float arr_coeff(const float* __restrict__ alpha,
                                           const float* __restrict__ beta,
                                           const float* __restrict__ gam,
                                           int k, float lt2, float nivt) {
    return alpha[k] * exp2f(fmaf(beta[k], lt2, gam[k] * nivt));
}

// ---------------------------------------------------------------------------
// Kernel 1: per-batch scalars.  One block per batch.
// ---------------------------------------------------------------------------
__global__ __launch_bounds__(TPB) void scalars_kernel(
    const float* __restrict__ y, const float* __restrict__ den_gas,
    const float* __restrict__ T_gas,
    const float* __restrict__ alpha, const float* __restrict__ beta,
    const float* __restrict__ gam,
    const int* __restrict__ k1g, const int* __restrict__ r1g,
    const int* __restrict__ p1g, const int* __restrict__ s1g,
    const int* __restrict__ k2g, const int* __restrict__ ra2g,
    const int* __restrict__ rb2g, const int* __restrict__ p2g,
    const int* __restrict__ s2g,
    const int* __restrict__ k1l, const int* __restrict__ r1l,
    const int* __restrict__ p1l, const int* __restrict__ s1l,
    const int* __restrict__ k2l, const int* __restrict__ ra2l,
    const int* __restrict__ rb2l, const int* __restrict__ p2l,
    const int* __restrict__ s2l,
    float* __restrict__ ws_k)            // [2*B]: {k_s2m, k_m2s} per batch
{
    __shared__ float ys[S_];
    __shared__ float red[4 * 4];         // 4 quantities x 4 waves

    const int b   = blockIdx.x;
    const int tid = threadIdx.x;
    const float* yb = y + b * S_;
    for (int i = tid; i < S_; i += TPB) ys[i] = yb[i];
    __syncthreads();

    const float T    = T_gas[b];
    const float den  = den_gas[b];
    const float lt2  = log2f(T * (1.0f / 300.0f));
    const float nivt = -LOG2E_ / T;

    // y_surf = sum ys[200:500), y_mant = sum ys[500:800)
    float vs = 0.f, vm = 0.f;
    for (int i = tid; i < 300; i += TPB) { vs += ys[200 + i]; vm += ys[500 + i]; }

    // gain: rates with product index in [200,500)
    float gain = 0.f;
    for (int e = tid; e < E1G_; e += TPB) {
        int p = p1g[e];
        if (p >= 200 && p < 500) {
            float c = arr_coeff(alpha, beta, gam, k1g[e], lt2, nivt);
            float r = c * ys[r1g[e]];
            gain += s1g[e] ? r : -r;
        }
    }
    for (int e = tid; e < E2G_; e += TPB) {
        int p = p2g[e];
        if (p >= 200 && p < 500) {
            float c = arr_coeff(alpha, beta, gam, k2g[e], lt2, nivt);
            float r = c * ys[ra2g[e]] * ys[rb2g[e]] * den;
            gain += s2g[e] ? r : -r;
        }
    }

    float loss = 0.f;
    for (int e = tid; e < E1L_; e += TPB) {
        int p = p1l[e];
        if (p >= 200 && p < 500) {
            float c = arr_coeff(alpha, beta, gam, k1l[e], lt2, nivt);
            float r = c * ys[r1l[e]];
            loss += s1l[e] ? r : -r;
        }
    }
    for (int e = tid; e < E2L_; e += TPB) {
        int p = p2l[e];
        if (p >= 200 && p < 500) {
            float c = arr_coeff(alpha, beta, gam, k2l[e], lt2, nivt);
            float r = c * ys[ra2l[e]] * ys[rb2l[e]] * den;
            loss += s2l[e] ? r : -r;
        }
    }

    // block reduction of {vs, vm, gain, loss}
    float vals[4] = {vs, vm, gain, loss};
    const int lane = tid & 63, wid = tid >> 6;
    #pragma unroll
    for (int q = 0; q < 4; ++q) {
        float v = vals[q];
        #pragma unroll
        for (int o = 32; o > 0; o >>= 1) v += __shfl_down(v, o, 64);
        if (lane == 0) red[q * 4 + wid] = v;
    }
    __syncthreads();

    if (tid == 0) {
        float t[4];
        #pragma unroll
        for (int q = 0; q < 4; ++q)
            t[q] = red[q*4+0] + red[q*4+1] + red[q*4+2] + red[q*4+3];
        float y_surf = t[0], y_mant = t[1], g_sum = t[2], l_sum = t[3];
        float n_layer = 1e-2f * (y_surf + y_mant);
        float decay = fminf(2.0f / fmaxf(n_layer, EPS_), 1.0f);
        // dy_surf_gain = g_sum ; dy_surf_loss = -l_sum
        float k_s2m = g_sum / fmaxf(y_surf, EPS_);
        float k_m2s = l_sum / fmaxf(y_mant, EPS_) * decay;
        ws_k[2 * b + 0] = k_s2m;
        ws_k[2 * b + 1] = k_m2s;
    }
}

// ---------------------------------------------------------------------------
// Kernel 2: final RHS assembly.  NCHUNK blocks per batch; LDS accumulator.
// ---------------------------------------------------------------------------
__global__ __launch_bounds__(TPB) void final_kernel(
    const float* __restrict__ y, const float* __restrict__ den_gas,
    const float* __restrict__ T_gas,
    const float* __restrict__ alpha, const float* __restrict__ beta,
    const float* __restrict__ gam,
    const int* __restrict__ k1, const int* __restrict__ r1,
    const int* __restrict__ p1, const int* __restrict__ s1,
    const int* __restrict__ k2, const int* __restrict__ ra2,
    const int* __restrict__ rb2, const int* __restrict__ p2,
    const int* __restrict__ s2,
    const float* __restrict__ ws_k,
    float* __restrict__ out)
{
    __shared__ float ys[S_];
    __shared__ float acc[S_];

    const int b = blockIdx.x / NCHUNK;
    const int c = blockIdx.x % NCHUNK;
    const int tid = threadIdx.x;

    const float* yb = y + b * S_;
    for (int i = tid; i < S_; i += TPB) { ys[i] = yb[i]; acc[i] = 0.0f; }
    __syncthreads();

    const float T    = T_gas[b];
    const float den  = den_gas[b];
    const float lt2  = log2f(T * (1.0f / 300.0f));
    const float nivt = -LOG2E_ / T;
    const float k_s2m = ws_k[2 * b + 0];
    const float k_m2s = ws_k[2 * b + 1];

    // 1st-order edges (coeff override for the smt swap range k < 1200)
    {
        const int e0 = c * (E1_ / NCHUNK);
        const int e1 = e0 + (E1_ / NCHUNK);
        for (int e = e0 + tid; e < e1; e += TPB) {
            int k = k1[e];
            float cf;
            if (k < NSMT_)          cf = k_s2m;
            else if (k < 2 * NSMT_) cf = k_m2s;
            else                    cf = arr_coeff(alpha, beta, gam, k, lt2, nivt);
            float r = cf * ys[r1[e]];
            atomicAdd(&acc[p1[e]], s1[e] ? r : -r);
        }
    }
    // 2nd-order edges (k2 >= N1 > 1200, never overridden)
    {
        const int e0 = c * (E2_ / NCHUNK);
        const int e1 = e0 + (E2_ / NCHUNK);
        for (int e = e0 + tid; e < e1; e += TPB) {
            float cf = arr_coeff(alpha, beta, gam, k2[e], lt2, nivt);
            float r = cf * ys[ra2[e]] * ys[rb2[e]] * den;
            atomicAdd(&acc[p2[e]], s2[e] ? r : -r);
        }
    }
    __syncthreads();

    float* ob = out + b * S_;
    for (int i = tid; i < S_; i += TPB) {
        float v = acc[i];
        if (v != 0.0f) atomicAdd(&ob[i], v);
    }
}

// ---------------------------------------------------------------------------
extern "C" void kernel_launch(void* const* d_in, const int* in_sizes, int n_in,
                              void* d_out, int out_size, void* d_ws, size_t ws_size,
                              hipStream_t stream) {
    // setup_inputs() order:
    //  0 t_in, 1 y_in, 2 den_gas, 3 T_gas, 4 alpha, 5 beta, 6 gamma,
    //  7 k1, 8 r1, 9 p1, 10 s1, 11 k2, 12 ra2, 13 rb2, 14 p2, 15 s2,
    // 16 k1g, 17 r1g, 18 p1g, 19 s1g, 20 k2g, 21 ra2g, 22 rb2g, 23 p2g, 24 s2g,
    // 25 k1l, 26 r1l, 27 p1l, 28 s1l, 29 k2l, 30 ra2l, 31 rb2l, 32 p2l, 33 s2l,
    // 34 inds_surf, 35 inds_mant, 36 inds_smt_s2m, 37 inds_smt_m2s (all fixed aranges)
    const float* y       = (const float*)d_in[1];
    const float* den_gas = (const float*)d_in[2];
    const float* T_gas   = (const float*)d_in[3];
    const float* alpha   = (const float*)d_in[4];
    const float* beta    = (const float*)d_in[5];
    const float* gam     = (const float*)d_in[6];
    const int* k1  = (const int*)d_in[7];
    const int* r1  = (const int*)d_in[8];
    const int* p1  = (const int*)d_in[9];
    const int* s1  = (const int*)d_in[10];
    const int* k2  = (const int*)d_in[11];
    const int* ra2 = (const int*)d_in[12];
    const int* rb2 = (const int*)d_in[13];
    const int* p2  = (const int*)d_in[14];
    const int* s2  = (const int*)d_in[15];
    const int* k1g  = (const int*)d_in[16];
    const int* r1g  = (const int*)d_in[17];
    const int* p1g  = (const int*)d_in[18];
    const int* s1g  = (const int*)d_in[19];
    const int* k2g  = (const int*)d_in[20];
    const int* ra2g = (const int*)d_in[21];
    const int* rb2g = (const int*)d_in[22];
    const int* p2g  = (const int*)d_in[23];
    const int* s2g  = (const int*)d_in[24];
    const int* k1l  = (const int*)d_in[25];
    const int* r1l  = (const int*)d_in[26];
    const int* p1l  = (const int*)d_in[27];
    const int* s1l  = (const int*)d_in[28];
    const int* k2l  = (const int*)d_in[29];
    const int* ra2l = (const int*)d_in[30];
    const int* rb2l = (const int*)d_in[31];
    const int* p2l  = (const int*)d_in[32];
    const int* s2l  = (const int*)d_in[33];

    float* ws_k = (float*)d_ws;                 // 2*B floats
    float* out  = (float*)d_out;

    hipMemsetAsync(d_out, 0, (size_t)out_size * sizeof(float), stream);

    scalars_kernel<<<B_, TPB, 0, stream>>>(
        y, den_gas, T_gas, alpha, beta, gam,
        k1g, r1g, p1g, s1g, k2g, ra2g, rb2g, p2g, s2g,
        k1l, r1l, p1l, s1l, k2l, ra2l, rb2l, p2l, s2l,
        ws_k);

    final_kernel<<<B_ * NCHUNK, TPB, 0, stream>>>(
        y, den_gas, T_gas, alpha, beta, gam,
        k1, r1, p1, s1, k2, ra2, rb2, p2, s2,
        ws_k, out);
}

// Round 2
// 377.699 us; speedup vs baseline: 2.9247x; 2.9247x over previous
//
#include <hip/hip_runtime.h>

// ThreePhaseTerm: sparse chemistry RHS assembly on MI355X.
//
// Round-2 structure (latency-bound fix):
//   K0 pack kernels: fold batch-independent per-edge data into ONE float4
//      stream per edge list: {sgn*alpha, beta, gamma, bits(r|p<<10|flag<<20)}.
//      - override edges (k<1200, final 1st-order) -> flag 1/2, a=+-1, b=g=0
//      - gain/loss edges with p outside [200,500) -> a=0 (masked, branch-free)
//   K1 gainloss_kernel (grid=B*GC): partial gain/loss sums -> atomicAdd ws
//   K2 final_kernel    (grid=B*NCHUNK): prologue recomputes y_surf/y_mant and
//      k_s2m/k_m2s from ws partials; 4x-unrolled edge loops; LDS accumulator;
//      global atomicAdd into zeroed d_out.

constexpr int B_    = 256;
constexpr int S_    = 800;
constexpr int E1_   = 60000;
constexpr int E2_   = 180000;
constexpr int E1G_  = 15000;
constexpr int E2G_  = 45000;
constexpr int E1L_  = 15000;
constexpr int E2L_  = 45000;
constexpr int NSMT_ = 600;
constexpr float LOG2E_ = 1.4426950408889634f;
constexpr float EPS_   = 1e-30f;
constexpr int   TPB    = 256;
constexpr int   NCHUNK = 8;   // final kernel: blocks per batch
constexpr int   GC     = 8;   // gainloss kernel: blocks per batch

// ---------------------------------------------------------------------------
// K0a: pack 1st-order edge list into float4 stream.
// ---------------------------------------------------------------------------
__global__ __launch_bounds__(256) void pack1_kernel(
    int E,
    const float* __restrict__ alpha, const float* __restrict__ beta,
    const float* __restrict__ gam,
    const int* __restrict__ k, const int* __restrict__ r,
    const int* __restrict__ p, const int* __restrict__ s,
    int do_override, int do_maskp, float4* __restrict__ out)
{
    int e = blockIdx.x * 256 + threadIdx.x;
    if (e >= E) return;
    int kk = k[e], rr = r[e], pp = p[e], ss = s[e];
    float a = alpha[kk], b = beta[kk], g = gam[kk];
    int flag = 0;
    if (do_override && kk < 2 * NSMT_) {
        flag = (kk < NSMT_) ? 1 : 2;
        a = 1.0f; b = 0.0f; g = 0.0f;   // exp2(0)=1; coeff provided at use site
    }
    if (do_maskp && !(pp >= 200 && pp < 500)) a = 0.0f;
    float a_s = ss ? a : -a;
    int bits = rr | (pp << 10) | (flag << 20);
    out[e] = make_float4(a_s, b, g, __int_as_float(bits));
}

// ---------------------------------------------------------------------------
// K0b: pack 2nd-order edge list into float4 stream.
// ---------------------------------------------------------------------------
__global__ __launch_bounds__(256) void pack2_kernel(
    int E,
    const float* __restrict__ alpha, const float* __restrict__ beta,
    const float* __restrict__ gam,
    const int* __restrict__ k, const int* __restrict__ ra,
    const int* __restrict__ rb, const int* __restrict__ p,
    const int* __restrict__ s,
    int do_maskp, float4* __restrict__ out)
{
    int e = blockIdx.x * 256 + threadIdx.x;
    if (e >= E) return;
    int kk = k[e], ia = ra[e], ib = rb[e], pp = p[e], ss = s[e];
    float a = alpha[kk], b = beta[kk], g = gam[kk];
    if (do_maskp && !(pp >= 200 && pp < 500)) a = 0.0f;
    float a_s = ss ? a : -a;
    int bits = ia | (ib << 10) | (pp << 20);
    out[e] = make_float4(a_s, b, g, __int_as_float(bits));
}

// ---------------------------------------------------------------------------
// rate helpers (packed-stream consumers)
// ---------------------------------------------------------------------------
__device__ __forceinline__ float rate1v(float4 q, const float* __restrict__ ys,
                                        float lt2, float nivt) {
    int bits = __float_as_int(q.w);
    int r = bits & 1023;
    return q.x * exp2f(fmaf(q.y, lt2, q.z * nivt)) * ys[r];
}

__device__ __forceinline__ float rate2v(float4 q, const float* __restrict__ ys,
                                        float lt2, float nivt, float den) {
    int bits = __float_as_int(q.w);
    int ra = bits & 1023, rb = (bits >> 10) & 1023;
    return q.x * exp2f(fmaf(q.y, lt2, q.z * nivt)) * ys[ra] * ys[rb] * den;
}

__device__ __forceinline__ void do1(float4 q, const float* __restrict__ ys,
                                    float* __restrict__ acc,
                                    float lt2, float nivt, float ks2m, float km2s) {
    int bits = __float_as_int(q.w);
    int r = bits & 1023, p = (bits >> 10) & 1023, flag = bits >> 20;
    float m = (flag == 0) ? 1.0f : ((flag == 1) ? ks2m : km2s);
    float rate = q.x * exp2f(fmaf(q.y, lt2, q.z * nivt)) * m * ys[r];
    atomicAdd(acc + p, rate);
}

__device__ __forceinline__ void do2(float4 q, const float* __restrict__ ys,
                                    float* __restrict__ acc,
                                    float lt2, float nivt, float den) {
    int bits = __float_as_int(q.w);
    int ra = bits & 1023, rb = (bits >> 10) & 1023, p = (bits >> 20) & 1023;
    float rate = q.x * exp2f(fmaf(q.y, lt2, q.z * nivt)) * ys[ra] * ys[rb] * den;
    atomicAdd(acc + p, rate);
}

// ---------------------------------------------------------------------------
// K1: per-batch gain/loss partial sums.  grid = B*GC.
// ---------------------------------------------------------------------------
__global__ __launch_bounds__(TPB) void gainloss_kernel(
    const float* __restrict__ y, const float* __restrict__ den_gas,
    const float* __restrict__ T_gas,
    const float4* __restrict__ g1, const float4* __restrict__ g2,
    const float4* __restrict__ l1, const float4* __restrict__ l2,
    float* __restrict__ part)            // [2*B] {gain, loss}, pre-zeroed
{
    __shared__ float ys[S_];
    __shared__ float red[2 * 4];

    const int b = blockIdx.x / GC;
    const int c = blockIdx.x % GC;
    const int tid = threadIdx.x;
    const float* yb = y + b * S_;
    for (int i = tid; i < S_; i += TPB) ys[i] = yb[i];
    __syncthreads();

    const float T    = T_gas[b];
    const float den  = den_gas[b];
    const float lt2  = log2f(T * (1.0f / 300.0f));
    const float nivt = -LOG2E_ / T;

    float gain = 0.f, loss = 0.f;
    // 1st-order slices (1875 edges each)
    {
        const int n = E1G_ / GC, e0 = c * n, e1 = e0 + n;
        for (int e = e0 + tid; e < e1; e += TPB) gain += rate1v(g1[e], ys, lt2, nivt);
        for (int e = e0 + tid; e < e1; e += TPB) loss += rate1v(l1[e], ys, lt2, nivt);
    }
    // 2nd-order slices (5625 edges each), 4x unrolled
    {
        const int n = E2G_ / GC, e0 = c * n, e1 = e0 + n;
        int e = e0 + tid;
        for (; e + 3 * TPB < e1; e += 4 * TPB) {
            float4 q0 = g2[e], q1 = g2[e + TPB], q2 = g2[e + 2 * TPB], q3 = g2[e + 3 * TPB];
            gain += rate2v(q0, ys, lt2, nivt, den) + rate2v(q1, ys, lt2, nivt, den)
                  + rate2v(q2, ys, lt2, nivt, den) + rate2v(q3, ys, lt2, nivt, den);
        }
        for (; e < e1; e += TPB) gain += rate2v(g2[e], ys, lt2, nivt, den);
        e = e0 + tid;
        for (; e + 3 * TPB < e1; e += 4 * TPB) {
            float4 q0 = l2[e], q1 = l2[e + TPB], q2 = l2[e + 2 * TPB], q3 = l2[e + 3 * TPB];
            loss += rate2v(q0, ys, lt2, nivt, den) + rate2v(q1, ys, lt2, nivt, den)
                  + rate2v(q2, ys, lt2, nivt, den) + rate2v(q3, ys, lt2, nivt, den);
        }
        for (; e < e1; e += TPB) loss += rate2v(l2[e], ys, lt2, nivt, den);
    }

    const int lane = tid & 63, wid = tid >> 6;
    #pragma unroll
    for (int o = 32; o > 0; o >>= 1) {
        gain += __shfl_down(gain, o, 64);
        loss += __shfl_down(loss, o, 64);
    }
    if (lane == 0) { red[wid] = gain; red[4 + wid] = loss; }
    __syncthreads();
    if (tid == 0) {
        atomicAdd(&part[2 * b + 0], red[0] + red[1] + red[2] + red[3]);
        atomicAdd(&part[2 * b + 1], red[4] + red[5] + red[6] + red[7]);
    }
}

// ---------------------------------------------------------------------------
// K2: final RHS assembly.  grid = B*NCHUNK; LDS accumulator; 4x unroll.
// ---------------------------------------------------------------------------
__global__ __launch_bounds__(TPB) void final_kernel(
    const float* __restrict__ y, const float* __restrict__ den_gas,
    const float* __restrict__ T_gas,
    const float4* __restrict__ f1, const float4* __restrict__ f2,
    const float* __restrict__ part,
    float* __restrict__ out)
{
    __shared__ float ys[S_];
    __shared__ float acc[S_];
    __shared__ float red[2 * 4];
    __shared__ float kpair[2];

    const int b = blockIdx.x / NCHUNK;
    const int c = blockIdx.x % NCHUNK;
    const int tid = threadIdx.x;

    const float* yb = y + b * S_;
    for (int i = tid; i < S_; i += TPB) { ys[i] = yb[i]; acc[i] = 0.0f; }
    __syncthreads();

    // prologue: y_surf / y_mant block reduction -> k_s2m, k_m2s
    float vs = 0.f, vm = 0.f;
    for (int i = tid; i < 300; i += TPB) { vs += ys[200 + i]; vm += ys[500 + i]; }
    const int lane = tid & 63, wid = tid >> 6;
    #pragma unroll
    for (int o = 32; o > 0; o >>= 1) {
        vs += __shfl_down(vs, o, 64);
        vm += __shfl_down(vm, o, 64);
    }
    if (lane == 0) { red[wid] = vs; red[4 + wid] = vm; }
    __syncthreads();
    if (tid == 0) {
        float y_surf = red[0] + red[1] + red[2] + red[3];
        float y_mant = red[4] + red[5] + red[6] + red[7];
        float gain = part[2 * b + 0], loss = part[2 * b + 1];
        float n_layer = 1e-2f * (y_surf + y_mant);
        float decay = fminf(2.0f / fmaxf(n_layer, EPS_), 1.0f);
        kpair[0] = gain / fmaxf(y_surf, EPS_);
        kpair[1] = loss / fmaxf(y_mant, EPS_) * decay;
    }
    __syncthreads();
    const float k_s2m = kpair[0];
    const float k_m2s = kpair[1];

    const float T    = T_gas[b];
    const float den  = den_gas[b];
    const float lt2  = log2f(T * (1.0f / 300.0f));
    const float nivt = -LOG2E_ / T;

    // 1st-order edges: 7500 per block
    {
        const int n = E1_ / NCHUNK, e0 = c * n, e1 = e0 + n;
        int e = e0 + tid;
        for (; e + 3 * TPB < e1; e += 4 * TPB) {
            float4 q0 = f1[e], q1 = f1[e + TPB], q2 = f1[e + 2 * TPB], q3 = f1[e + 3 * TPB];
            do1(q0, ys, acc, lt2, nivt, k_s2m, k_m2s);
            do1(q1, ys, acc, lt2, nivt, k_s2m, k_m2s);
            do1(q2, ys, acc, lt2, nivt, k_s2m, k_m2s);
            do1(q3, ys, acc, lt2, nivt, k_s2m, k_m2s);
        }
        for (; e < e1; e += TPB) do1(f1[e], ys, acc, lt2, nivt, k_s2m, k_m2s);
    }
    // 2nd-order edges: 22500 per block
    {
        const int n = E2_ / NCHUNK, e0 = c * n, e1 = e0 + n;
        int e = e0 + tid;
        for (; e + 3 * TPB < e1; e += 4 * TPB) {
            float4 q0 = f2[e], q1 = f2[e + TPB], q2 = f2[e + 2 * TPB], q3 = f2[e + 3 * TPB];
            do2(q0, ys, acc, lt2, nivt, den);
            do2(q1, ys, acc, lt2, nivt, den);
            do2(q2, ys, acc, lt2, nivt, den);
            do2(q3, ys, acc, lt2, nivt, den);
        }
        for (; e < e1; e += TPB) do2(f2[e], ys, acc, lt2, nivt, den);
    }
    __syncthreads();

    float* ob = out + b * S_;
    for (int i = tid; i < S_; i += TPB) {
        float v = acc[i];
        if (v != 0.0f) atomicAdd(&ob[i], v);
    }
}

// ---------------------------------------------------------------------------
extern "C" void kernel_launch(void* const* d_in, const int* in_sizes, int n_in,
                              void* d_out, int out_size, void* d_ws, size_t ws_size,
                              hipStream_t stream) {
    const float* y       = (const float*)d_in[1];
    const float* den_gas = (const float*)d_in[2];
    const float* T_gas   = (const float*)d_in[3];
    const float* alpha   = (const float*)d_in[4];
    const float* beta    = (const float*)d_in[5];
    const float* gam     = (const float*)d_in[6];
    const int* k1  = (const int*)d_in[7];
    const int* r1  = (const int*)d_in[8];
    const int* p1  = (const int*)d_in[9];
    const int* s1  = (const int*)d_in[10];
    const int* k2  = (const int*)d_in[11];
    const int* ra2 = (const int*)d_in[12];
    const int* rb2 = (const int*)d_in[13];
    const int* p2  = (const int*)d_in[14];
    const int* s2  = (const int*)d_in[15];
    const int* k1g  = (const int*)d_in[16];
    const int* r1g  = (const int*)d_in[17];
    const int* p1g  = (const int*)d_in[18];
    const int* s1g  = (const int*)d_in[19];
    const int* k2g  = (const int*)d_in[20];
    const int* ra2g = (const int*)d_in[21];
    const int* rb2g = (const int*)d_in[22];
    const int* p2g  = (const int*)d_in[23];
    const int* s2g  = (const int*)d_in[24];
    const int* k1l  = (const int*)d_in[25];
    const int* r1l  = (const int*)d_in[26];
    const int* p1l  = (const int*)d_in[27];
    const int* s1l  = (const int*)d_in[28];
    const int* k2l  = (const int*)d_in[29];
    const int* ra2l = (const int*)d_in[30];
    const int* rb2l = (const int*)d_in[31];
    const int* p2l  = (const int*)d_in[32];
    const int* s2l  = (const int*)d_in[33];

    // workspace layout
    char* w = (char*)d_ws;
    size_t off = 0;
    float4* f1 = (float4*)(w + off); off += (size_t)E1_  * 16;
    float4* f2 = (float4*)(w + off); off += (size_t)E2_  * 16;
    float4* g1 = (float4*)(w + off); off += (size_t)E1G_ * 16;
    float4* g2 = (float4*)(w + off); off += (size_t)E2G_ * 16;
    float4* l1 = (float4*)(w + off); off += (size_t)E1L_ * 16;
    float4* l2 = (float4*)(w + off); off += (size_t)E2L_ * 16;
    float*  part = (float*)(w + off); off += (size_t)2 * B_ * 4;

    float* out = (float*)d_out;

    hipMemsetAsync(d_out, 0, (size_t)out_size * sizeof(float), stream);
    hipMemsetAsync(part, 0, (size_t)2 * B_ * sizeof(float), stream);

    // K0: pack streams (batch-independent)
    pack1_kernel<<<(E1_  + 255) / 256, 256, 0, stream>>>(E1_,  alpha, beta, gam, k1,  r1,  p1,  s1,  1, 0, f1);
    pack2_kernel<<<(E2_  + 255) / 256, 256, 0, stream>>>(E2_,  alpha, beta, gam, k2,  ra2, rb2, p2,  s2, 0, f2);
    pack1_kernel<<<(E1G_ + 255) / 256, 256, 0, stream>>>(E1G_, alpha, beta, gam, k1g, r1g, p1g, s1g, 0, 1, g1);
    pack2_kernel<<<(E2G_ + 255) / 256, 256, 0, stream>>>(E2G_, alpha, beta, gam, k2g, ra2g, rb2g, p2g, s2g, 1, g2);
    pack1_kernel<<<(E1L_ + 255) / 256, 256, 0, stream>>>(E1L_, alpha, beta, gam, k1l, r1l, p1l, s1l, 0, 1, l1);
    pack2_kernel<<<(E2L_ + 255) / 256, 256, 0, stream>>>(E2L_, alpha, beta, gam, k2l, ra2l, rb2l, p2l, s2l, 1, l2);

    // K1: gain/loss partial sums
    gainloss_kernel<<<B_ * GC, TPB, 0, stream>>>(y, den_gas, T_gas, g1, g2, l1, l2, part);

    // K2: final assembly
    final_kernel<<<B_ * NCHUNK, TPB, 0, stream>>>(y, den_gas, T_gas, f1, f2, part, out);
}

// Round 3
// 375.175 us; speedup vs baseline: 2.9444x; 1.0067x over previous
//
#include <hip/hip_runtime.h>

// ThreePhaseTerm: sparse chemistry RHS assembly on MI355X.
//
// Round-3 structure (latency amortization):
//   Packed per-edge float4 streams (batch-independent) as in round 2, but the
//   consumer kernels now process MB=4 batches per block: one 16B stream load
//   feeds 4 independent {fma+exp2+LDS gather+LDS atomic} chains. 2x manual
//   unroll on top -> 8 chains in flight per thread. Stream L2 traffic /4.

constexpr int B_    = 256;
constexpr int S_    = 800;
constexpr int E1_   = 60000;
constexpr int E2_   = 180000;
constexpr int E1G_  = 15000;
constexpr int E2G_  = 45000;
constexpr int E1L_  = 15000;
constexpr int E2L_  = 45000;
constexpr int NSMT_ = 600;
constexpr float LOG2E_ = 1.4426950408889634f;
constexpr float EPS_   = 1e-30f;
constexpr int TPB    = 256;
constexpr int MB     = 4;           // batches per block
constexpr int NBG    = B_ / MB;     // 64 batch groups
constexpr int NCHUNK = 24;          // final kernel: edge chunks  (64*24=1536 blocks)
constexpr int GC     = 24;          // gainloss kernel: edge chunks

// ---------------------------------------------------------------------------
// K0a: pack 1st-order final edges: {sgn*alpha, beta, gamma, r|p<<10|flag<<20}
// flag: 0 = plain Arrhenius, 1 = k_s2m override, 2 = k_m2s override.
// ---------------------------------------------------------------------------
__global__ __launch_bounds__(256) void pack1_kernel(
    int E,
    const float* __restrict__ alpha, const float* __restrict__ beta,
    const float* __restrict__ gam,
    const int* __restrict__ k, const int* __restrict__ r,
    const int* __restrict__ p, const int* __restrict__ s,
    float4* __restrict__ out)
{
    int e = blockIdx.x * 256 + threadIdx.x;
    if (e >= E) return;
    int kk = k[e], rr = r[e], pp = p[e], ss = s[e];
    float a = alpha[kk], b = beta[kk], g = gam[kk];
    int flag = 0;
    if (kk < 2 * NSMT_) {
        flag = (kk < NSMT_) ? 1 : 2;
        a = 1.0f; b = 0.0f; g = 0.0f;   // exp2(0)=1; override coeff at use site
    }
    float a_s = ss ? a : -a;
    int bits = rr | (pp << 10) | (flag << 20);
    out[e] = make_float4(a_s, b, g, __int_as_float(bits));
}

// ---------------------------------------------------------------------------
// K0b: pack 2nd-order final edges: {sgn*alpha, beta, gamma, ra|rb<<10|p<<20}
// ---------------------------------------------------------------------------
__global__ __launch_bounds__(256) void pack2_kernel(
    int E,
    const float* __restrict__ alpha, const float* __restrict__ beta,
    const float* __restrict__ gam,
    const int* __restrict__ k, const int* __restrict__ ra,
    const int* __restrict__ rb, const int* __restrict__ p,
    const int* __restrict__ s,
    int do_maskp, float4* __restrict__ out)
{
    int e = blockIdx.x * 256 + threadIdx.x;
    if (e >= E) return;
    int kk = k[e], ia = ra[e], ib = rb[e], pp = p[e], ss = s[e];
    float a = alpha[kk], b = beta[kk], g = gam[kk];
    if (do_maskp && !(pp >= 200 && pp < 500)) a = 0.0f;
    float a_s = ss ? a : -a;
    int bits = ia | (ib << 10) | (pp << 20);
    out[e] = make_float4(a_s, b, g, __int_as_float(bits));
}

// ---------------------------------------------------------------------------
// K0c: pack 1st-order gain/loss edges (reduction-only; p folded into mask).
// bits = r.
// ---------------------------------------------------------------------------
__global__ __launch_bounds__(256) void pack1gl_kernel(
    int E,
    const float* __restrict__ alpha, const float* __restrict__ beta,
    const float* __restrict__ gam,
    const int* __restrict__ k, const int* __restrict__ r,
    const int* __restrict__ p, const int* __restrict__ s,
    float4* __restrict__ out)
{
    int e = blockIdx.x * 256 + threadIdx.x;
    if (e >= E) return;
    int kk = k[e], rr = r[e], pp = p[e], ss = s[e];
    float a = alpha[kk], b = beta[kk], g = gam[kk];
    if (!(pp >= 200 && pp < 500)) a = 0.0f;
    float a_s = ss ? a : -a;
    out[e] = make_float4(a_s, b, g, __int_as_float(rr));
}

// ---------------------------------------------------------------------------
// helpers (forceinlined; all mb indexing compile-time via #pragma unroll)
// ---------------------------------------------------------------------------
__device__ __forceinline__ void do1_final(
    float4 q, const float (*ys)[S_], float (*acc)[S_],
    const float (&lt2)[MB], const float (&nivt)[MB],
    const float (&ks)[MB], const float (&km)[MB])
{
    int bits = __float_as_int(q.w);
    int r = bits & 1023, p = (bits >> 10) & 1023, fl = bits >> 20;
    #pragma unroll
    for (int mb = 0; mb < MB; ++mb) {
        float m = (fl == 0) ? 1.0f : ((fl == 1) ? ks[mb] : km[mb]);
        float rate = q.x * exp2f(fmaf(q.y, lt2[mb], q.z * nivt[mb])) * m * ys[mb][r];
        atomicAdd(&acc[mb][p], rate);
    }
}

__device__ __forceinline__ void do2_final(
    float4 q, const float (*ys)[S_], float (*acc)[S_],
    const float (&lt2)[MB], const float (&nivt)[MB], const float (&den)[MB])
{
    int bits = __float_as_int(q.w);
    int ra = bits & 1023, rb = (bits >> 10) & 1023, p = (bits >> 20) & 1023;
    #pragma unroll
    for (int mb = 0; mb < MB; ++mb) {
        float rate = q.x * exp2f(fmaf(q.y, lt2[mb], q.z * nivt[mb]))
                   * ys[mb][ra] * ys[mb][rb] * den[mb];
        atomicAdd(&acc[mb][p], rate);
    }
}

__device__ __forceinline__ void red1_gl(
    float4 q, const float (*ys)[S_],
    const float (&lt2)[MB], const float (&nivt)[MB], float (&s)[MB])
{
    int r = __float_as_int(q.w) & 1023;
    #pragma unroll
    for (int mb = 0; mb < MB; ++mb)
        s[mb] += q.x * exp2f(fmaf(q.y, lt2[mb], q.z * nivt[mb])) * ys[mb][r];
}

__device__ __forceinline__ void red2_gl(
    float4 q, const float (*ys)[S_],
    const float (&lt2)[MB], const float (&nivt)[MB], const float (&den)[MB],
    float (&s)[MB])
{
    int bits = __float_as_int(q.w);
    int ra = bits & 1023, rb = (bits >> 10) & 1023;
    #pragma unroll
    for (int mb = 0; mb < MB; ++mb)
        s[mb] += q.x * exp2f(fmaf(q.y, lt2[mb], q.z * nivt[mb]))
               * ys[mb][ra] * ys[mb][rb] * den[mb];
}

// ---------------------------------------------------------------------------
// K1: gain/loss partial sums.  grid = NBG*GC, MB batches per block.
// ---------------------------------------------------------------------------
__global__ __launch_bounds__(TPB) void gainloss_kernel(
    const float* __restrict__ y, const float* __restrict__ den_gas,
    const float* __restrict__ T_gas,
    const float4* __restrict__ g1, const float4* __restrict__ g2,
    const float4* __restrict__ l1, const float4* __restrict__ l2,
    float* __restrict__ part)            // [2*B] {gain, loss}, pre-zeroed
{
    __shared__ float ys[MB][S_];
    __shared__ float red[4][MB][2];

    const int bg = blockIdx.x / GC;
    const int c  = blockIdx.x % GC;
    const int b0 = bg * MB;
    const int tid = threadIdx.x;

    #pragma unroll
    for (int mb = 0; mb < MB; ++mb)
        for (int i = tid; i < S_; i += TPB) ys[mb][i] = y[(b0 + mb) * S_ + i];
    __syncthreads();

    float lt2[MB], nivt[MB], den[MB];
    #pragma unroll
    for (int mb = 0; mb < MB; ++mb) {
        float T  = T_gas[b0 + mb];
        den[mb]  = den_gas[b0 + mb];
        lt2[mb]  = log2f(T * (1.0f / 300.0f));
        nivt[mb] = -LOG2E_ / T;
    }

    float gain[MB] = {0, 0, 0, 0}, loss[MB] = {0, 0, 0, 0};

    {   // 1st-order, 625 edges per chunk each
        const int n = E1G_ / GC, e0 = c * n, e1 = e0 + n;
        for (int e = e0 + tid; e < e1; e += TPB) red1_gl(g1[e], ys, lt2, nivt, gain);
        for (int e = e0 + tid; e < e1; e += TPB) red1_gl(l1[e], ys, lt2, nivt, loss);
    }
    {   // 2nd-order gain, 1875 per chunk, unroll 2
        const int n = E2G_ / GC, e0 = c * n, e1 = e0 + n;
        int e = e0 + tid;
        for (; e + TPB < e1; e += 2 * TPB) {
            float4 q0 = g2[e], q1 = g2[e + TPB];
            red2_gl(q0, ys, lt2, nivt, den, gain);
            red2_gl(q1, ys, lt2, nivt, den, gain);
        }
        for (; e < e1; e += TPB) red2_gl(g2[e], ys, lt2, nivt, den, gain);
    }
    {   // 2nd-order loss
        const int n = E2L_ / GC, e0 = c * n, e1 = e0 + n;
        int e = e0 + tid;
        for (; e + TPB < e1; e += 2 * TPB) {
            float4 q0 = l2[e], q1 = l2[e + TPB];
            red2_gl(q0, ys, lt2, nivt, den, loss);
            red2_gl(q1, ys, lt2, nivt, den, loss);
        }
        for (; e < e1; e += TPB) red2_gl(l2[e], ys, lt2, nivt, den, loss);
    }

    const int lane = tid & 63, wid = tid >> 6;
    #pragma unroll
    for (int mb = 0; mb < MB; ++mb) {
        float g = gain[mb], l = loss[mb];
        #pragma unroll
        for (int o = 32; o > 0; o >>= 1) {
            g += __shfl_down(g, o, 64);
            l += __shfl_down(l, o, 64);
        }
        if (lane == 0) { red[wid][mb][0] = g; red[wid][mb][1] = l; }
    }
    __syncthreads();
    if (tid < 2 * MB) {
        int mb = tid >> 1, gl = tid & 1;
        float v = red[0][mb][gl] + red[1][mb][gl] + red[2][mb][gl] + red[3][mb][gl];
        atomicAdd(&part[2 * (b0 + mb) + gl], v);
    }
}

// ---------------------------------------------------------------------------
// K2: final RHS assembly.  grid = NBG*NCHUNK, MB batches per block.
// ---------------------------------------------------------------------------
__global__ __launch_bounds__(TPB, 6) void final_kernel(
    const float* __restrict__ y, const float* __restrict__ den_gas,
    const float* __restrict__ T_gas,
    const float4* __restrict__ f1, const float4* __restrict__ f2,
    const float* __restrict__ part,
    float* __restrict__ out)
{
    __shared__ float ys[MB][S_];
    __shared__ float acc[MB][S_];
    __shared__ float ksm[MB][2];

    const int bg = blockIdx.x / NCHUNK;
    const int c  = blockIdx.x % NCHUNK;
    const int b0 = bg * MB;
    const int tid = threadIdx.x, lane = tid & 63, wid = tid >> 6;

    #pragma unroll
    for (int mb = 0; mb < MB; ++mb)
        for (int i = tid; i < S_; i += TPB) {
            ys[mb][i] = y[(b0 + mb) * S_ + i];
            acc[mb][i] = 0.0f;
        }
    __syncthreads();

    // wave `wid` derives k_s2m/k_m2s for batch b0+wid
    {
        const int mb = wid;
        float vs = 0.f, vm = 0.f;
        for (int i = lane; i < 300; i += 64) { vs += ys[mb][200 + i]; vm += ys[mb][500 + i]; }
        #pragma unroll
        for (int o = 32; o > 0; o >>= 1) {
            vs += __shfl_down(vs, o, 64);
            vm += __shfl_down(vm, o, 64);
        }
        if (lane == 0) {
            float y_surf = vs, y_mant = vm;
            float gain = part[2 * (b0 + mb) + 0], loss = part[2 * (b0 + mb) + 1];
            float n_layer = 1e-2f * (y_surf + y_mant);
            float decay = fminf(2.0f / fmaxf(n_layer, EPS_), 1.0f);
            ksm[mb][0] = gain / fmaxf(y_surf, EPS_);
            ksm[mb][1] = loss / fmaxf(y_mant, EPS_) * decay;
        }
    }
    __syncthreads();

    float ks[MB], km[MB], lt2[MB], nivt[MB], den[MB];
    #pragma unroll
    for (int mb = 0; mb < MB; ++mb) {
        ks[mb] = ksm[mb][0];
        km[mb] = ksm[mb][1];
        float T  = T_gas[b0 + mb];
        den[mb]  = den_gas[b0 + mb];
        lt2[mb]  = log2f(T * (1.0f / 300.0f));
        nivt[mb] = -LOG2E_ / T;
    }

    {   // 1st-order edges: 2500 per chunk, unroll 2
        const int n = E1_ / NCHUNK, e0 = c * n, e1 = e0 + n;
        int e = e0 + tid;
        for (; e + TPB < e1; e += 2 * TPB) {
            float4 q0 = f1[e], q1 = f1[e + TPB];
            do1_final(q0, ys, acc, lt2, nivt, ks, km);
            do1_final(q1, ys, acc, lt2, nivt, ks, km);
        }
        for (; e < e1; e += TPB) do1_final(f1[e], ys, acc, lt2, nivt, ks, km);
    }
    {   // 2nd-order edges: 7500 per chunk, unroll 2
        const int n = E2_ / NCHUNK, e0 = c * n, e1 = e0 + n;
        int e = e0 + tid;
        for (; e + TPB < e1; e += 2 * TPB) {
            float4 q0 = f2[e], q1 = f2[e + TPB];
            do2_final(q0, ys, acc, lt2, nivt, den);
            do2_final(q1, ys, acc, lt2, nivt, den);
        }
        for (; e < e1; e += TPB) do2_final(f2[e], ys, acc, lt2, nivt, den);
    }
    __syncthreads();

    // wave `wid` flushes batch b0+wid (coalesced per wave)
    {
        float* ob = out + (b0 + wid) * S_;
        for (int i = lane; i < S_; i += 64) atomicAdd(&ob[i], acc[wid][i]);
    }
}

// ---------------------------------------------------------------------------
extern "C" void kernel_launch(void* const* d_in, const int* in_sizes, int n_in,
                              void* d_out, int out_size, void* d_ws, size_t ws_size,
                              hipStream_t stream) {
    const float* y       = (const float*)d_in[1];
    const float* den_gas = (const float*)d_in[2];
    const float* T_gas   = (const float*)d_in[3];
    const float* alpha   = (const float*)d_in[4];
    const float* beta    = (const float*)d_in[5];
    const float* gam     = (const float*)d_in[6];
    const int* k1  = (const int*)d_in[7];
    const int* r1  = (const int*)d_in[8];
    const int* p1  = (const int*)d_in[9];
    const int* s1  = (const int*)d_in[10];
    const int* k2  = (const int*)d_in[11];
    const int* ra2 = (const int*)d_in[12];
    const int* rb2 = (const int*)d_in[13];
    const int* p2  = (const int*)d_in[14];
    const int* s2  = (const int*)d_in[15];
    const int* k1g  = (const int*)d_in[16];
    const int* r1g  = (const int*)d_in[17];
    const int* p1g  = (const int*)d_in[18];
    const int* s1g  = (const int*)d_in[19];
    const int* k2g  = (const int*)d_in[20];
    const int* ra2g = (const int*)d_in[21];
    const int* rb2g = (const int*)d_in[22];
    const int* p2g  = (const int*)d_in[23];
    const int* s2g  = (const int*)d_in[24];
    const int* k1l  = (const int*)d_in[25];
    const int* r1l  = (const int*)d_in[26];
    const int* p1l  = (const int*)d_in[27];
    const int* s1l  = (const int*)d_in[28];
    const int* k2l  = (const int*)d_in[29];
    const int* ra2l = (const int*)d_in[30];
    const int* rb2l = (const int*)d_in[31];
    const int* p2l  = (const int*)d_in[32];
    const int* s2l  = (const int*)d_in[33];

    // workspace layout
    char* w = (char*)d_ws;
    size_t off = 0;
    float4* f1 = (float4*)(w + off); off += (size_t)E1_  * 16;
    float4* f2 = (float4*)(w + off); off += (size_t)E2_  * 16;
    float4* g1 = (float4*)(w + off); off += (size_t)E1G_ * 16;
    float4* g2 = (float4*)(w + off); off += (size_t)E2G_ * 16;
    float4* l1 = (float4*)(w + off); off += (size_t)E1L_ * 16;
    float4* l2 = (float4*)(w + off); off += (size_t)E2L_ * 16;
    float*  part = (float*)(w + off); off += (size_t)2 * B_ * 4;

    float* out = (float*)d_out;

    hipMemsetAsync(d_out, 0, (size_t)out_size * sizeof(float), stream);
    hipMemsetAsync(part, 0, (size_t)2 * B_ * sizeof(float), stream);

    // K0: pack streams (batch-independent)
    pack1_kernel  <<<(E1_  + 255) / 256, 256, 0, stream>>>(E1_,  alpha, beta, gam, k1,  r1,  p1,  s1,  f1);
    pack2_kernel  <<<(E2_  + 255) / 256, 256, 0, stream>>>(E2_,  alpha, beta, gam, k2,  ra2, rb2, p2,  s2, 0, f2);
    pack1gl_kernel<<<(E1G_ + 255) / 256, 256, 0, stream>>>(E1G_, alpha, beta, gam, k1g, r1g, p1g, s1g, g1);
    pack2_kernel  <<<(E2G_ + 255) / 256, 256, 0, stream>>>(E2G_, alpha, beta, gam, k2g, ra2g, rb2g, p2g, s2g, 1, g2);
    pack1gl_kernel<<<(E1L_ + 255) / 256, 256, 0, stream>>>(E1L_, alpha, beta, gam, k1l, r1l, p1l, s1l, l1);
    pack2_kernel  <<<(E2L_ + 255) / 256, 256, 0, stream>>>(E2L_, alpha, beta, gam, k2l, ra2l, rb2l, p2l, s2l, 1, l2);

    // K1: gain/loss partial sums
    gainloss_kernel<<<NBG * GC, TPB, 0, stream>>>(y, den_gas, T_gas, g1, g2, l1, l2, part);

    // K2: final assembly
    final_kernel<<<NBG * NCHUNK, TPB, 0, stream>>>(y, den_gas, T_gas, f1, f2, part, out);
}

// Round 4
// 140.953 us; speedup vs baseline: 7.8371x; 2.6617x over previous
//
#include <hip/hip_runtime.h>

// ThreePhaseTerm: sparse chemistry RHS assembly on MI355X.
//
// Round-4 structure (kill the LDS-atomic pipe bottleneck):
//   Rounds 2/3 were throughput-bound on LDS atomicAdd (61.4M lane-RMWs,
//   ~216 cy/wave-atomic -> 338us invariant). This round sorts the final
//   edge list by product p (device counting sort, batch-independent, done
//   every launch) and turns the scatter into a register-accumulated GATHER:
//   one wave per (product-run, 4 batches), lanes stride the contiguous edge
//   run, shuffle-reduce, direct store. No atomics in the hot path.
//   Unified operand encoding: rate = a_s*exp2(b*lt2+g*nivt)*ys[ia]*w[ib],
//   w[i<800]=ys[i]*den (2nd order), w[800]=1 (1st), w[801]=k_s2m, w[802]=k_m2s.

constexpr int B_    = 256;
constexpr int S_    = 800;
constexpr int E1_   = 60000;
constexpr int E2_   = 180000;
constexpr int ET_   = E1_ + E2_;      // 240000 combined final edges
constexpr int E1G_  = 15000;
constexpr int E2G_  = 45000;
constexpr int E1L_  = 15000;
constexpr int E2L_  = 45000;
constexpr int NSMT_ = 600;
constexpr float LOG2E_ = 1.4426950408889634f;
constexpr float EPS_   = 1e-30f;
constexpr int TPB  = 256;
constexpr int MB   = 4;               // batches per block (== waves per block)
constexpr int NBG  = B_ / MB;         // 64 batch groups
constexpr int GC   = 24;              // gainloss kernel edge chunks
constexpr int PPB  = 16;              // products per block (final gather)
constexpr int PPW  = 4;               // products per wave
constexpr int PC   = S_ / PPB;        // 50 product chunks
constexpr int PAD  = 16;              // int stride for atomic counters (64B)
// unified second-operand indices
constexpr int IB_ONE = 800, IB_KS = 801, IB_KM = 802, WW = 804;

// ---------------------------------------------------------------------------
// Sort phase A: histogram of product indices (padded counters, pre-zeroed).
// ---------------------------------------------------------------------------
__global__ __launch_bounds__(256) void hist_kernel(
    const int* __restrict__ p1, const int* __restrict__ p2,
    int* __restrict__ cnt)
{
    int e = blockIdx.x * 256 + threadIdx.x;
    if (e < E1_)      atomicAdd(&cnt[p1[e] * PAD], 1);
    else if (e < ET_) atomicAdd(&cnt[p2[e - E1_] * PAD], 1);
}

// ---------------------------------------------------------------------------
// Sort phase B: exclusive scan of 800 bins (one block), init rank counters.
// ---------------------------------------------------------------------------
__global__ __launch_bounds__(1024) void scan_kernel(
    const int* __restrict__ cnt, int* __restrict__ starts,
    int* __restrict__ rank)
{
    __shared__ int sc[1024];
    int t = threadIdx.x;
    sc[t] = (t < S_) ? cnt[t * PAD] : 0;
    __syncthreads();
    for (int off = 1; off < 1024; off <<= 1) {
        int v = (t >= off) ? sc[t - off] : 0;
        __syncthreads();
        sc[t] += v;
        __syncthreads();
    }
    if (t < S_) {
        int ex = t ? sc[t - 1] : 0;
        starts[t] = ex;
        rank[t * PAD] = ex;
    }
    if (t == S_ - 1) starts[S_] = sc[t];
}

// ---------------------------------------------------------------------------
// Sort phase C: reorder+pack 1st-order final edges into sorted stream.
// bits = ia | ib<<10 ; ib in {800 (plain), 801 (k_s2m), 802 (k_m2s)}.
// ---------------------------------------------------------------------------
__global__ __launch_bounds__(256) void reorder1_kernel(
    const float* __restrict__ alpha, const float* __restrict__ beta,
    const float* __restrict__ gam,
    const int* __restrict__ k, const int* __restrict__ r,
    const int* __restrict__ p, const int* __restrict__ s,
    int* __restrict__ rank, float4* __restrict__ sorted)
{
    int e = blockIdx.x * 256 + threadIdx.x;
    if (e >= E1_) return;
    int kk = k[e], rr = r[e], pp = p[e], ss = s[e];
    float a = alpha[kk], b = beta[kk], g = gam[kk];
    int ib = IB_ONE;
    if (kk < 2 * NSMT_) {
        ib = (kk < NSMT_) ? IB_KS : IB_KM;
        a = 1.0f; b = 0.0f; g = 0.0f;    // exp2(0)=1; override coeff via w[ib]
    }
    float a_s = ss ? a : -a;
    int bits = rr | (ib << 10);
    int slot = atomicAdd(&rank[pp * PAD], 1);
    sorted[slot] = make_float4(a_s, b, g, __int_as_float(bits));
}

// ---------------------------------------------------------------------------
// Sort phase C': reorder+pack 2nd-order final edges. bits = ra | rb<<10.
// ---------------------------------------------------------------------------
__global__ __launch_bounds__(256) void reorder2_kernel(
    const float* __restrict__ alpha, const float* __restrict__ beta,
    const float* __restrict__ gam,
    const int* __restrict__ k, const int* __restrict__ ra,
    const int* __restrict__ rb, const int* __restrict__ p,
    const int* __restrict__ s,
    int* __restrict__ rank, float4* __restrict__ sorted)
{
    int e = blockIdx.x * 256 + threadIdx.x;
    if (e >= E2_) return;
    int kk = k[e], ia = ra[e], ib = rb[e], pp = p[e], ss = s[e];
    float a = alpha[kk], b = beta[kk], g = gam[kk];
    float a_s = ss ? a : -a;
    int bits = ia | (ib << 10);
    int slot = atomicAdd(&rank[pp * PAD], 1);
    sorted[slot] = make_float4(a_s, b, g, __int_as_float(bits));
}

// ---------------------------------------------------------------------------
// Pack gain/loss streams (reduction-only; p folded into sign/zero mask).
// ---------------------------------------------------------------------------
__global__ __launch_bounds__(256) void pack1gl_kernel(
    int E,
    const float* __restrict__ alpha, const float* __restrict__ beta,
    const float* __restrict__ gam,
    const int* __restrict__ k, const int* __restrict__ r,
    const int* __restrict__ p, const int* __restrict__ s,
    float4* __restrict__ out)
{
    int e = blockIdx.x * 256 + threadIdx.x;
    if (e >= E) return;
    int kk = k[e], rr = r[e], pp = p[e], ss = s[e];
    float a = alpha[kk], b = beta[kk], g = gam[kk];
    if (!(pp >= 200 && pp < 500)) a = 0.0f;
    float a_s = ss ? a : -a;
    out[e] = make_float4(a_s, b, g, __int_as_float(rr));
}

__global__ __launch_bounds__(256) void pack2gl_kernel(
    int E,
    const float* __restrict__ alpha, const float* __restrict__ beta,
    const float* __restrict__ gam,
    const int* __restrict__ k, const int* __restrict__ ra,
    const int* __restrict__ rb, const int* __restrict__ p,
    const int* __restrict__ s,
    float4* __restrict__ out)
{
    int e = blockIdx.x * 256 + threadIdx.x;
    if (e >= E) return;
    int kk = k[e], ia = ra[e], ib = rb[e], pp = p[e], ss = s[e];
    float a = alpha[kk], b = beta[kk], g = gam[kk];
    if (!(pp >= 200 && pp < 500)) a = 0.0f;
    float a_s = ss ? a : -a;
    int bits = ia | (ib << 10);
    out[e] = make_float4(a_s, b, g, __int_as_float(bits));
}

// ---------------------------------------------------------------------------
// gain/loss helpers
// ---------------------------------------------------------------------------
__device__ __forceinline__ void red1_gl(
    float4 q, const float (*ys)[S_],
    const float (&lt2)[MB], const float (&nivt)[MB], float (&s)[MB])
{
    int r = __float_as_int(q.w) & 1023;
    #pragma unroll
    for (int mb = 0; mb < MB; ++mb)
        s[mb] += q.x * exp2f(fmaf(q.y, lt2[mb], q.z * nivt[mb])) * ys[mb][r];
}

__device__ __forceinline__ void red2_gl(
    float4 q, const float (*ys)[S_],
    const float (&lt2)[MB], const float (&nivt)[MB], const float (&den)[MB],
    float (&s)[MB])
{
    int bits = __float_as_int(q.w);
    int ra = bits & 1023, rb = (bits >> 10) & 1023;
    #pragma unroll
    for (int mb = 0; mb < MB; ++mb)
        s[mb] += q.x * exp2f(fmaf(q.y, lt2[mb], q.z * nivt[mb]))
               * ys[mb][ra] * ys[mb][rb] * den[mb];
}

// ---------------------------------------------------------------------------
// K1: gain/loss partial sums.  grid = NBG*GC, MB batches per block.
// ---------------------------------------------------------------------------
__global__ __launch_bounds__(TPB) void gainloss_kernel(
    const float* __restrict__ y, const float* __restrict__ den_gas,
    const float* __restrict__ T_gas,
    const float4* __restrict__ g1, const float4* __restrict__ g2,
    const float4* __restrict__ l1, const float4* __restrict__ l2,
    float* __restrict__ part)            // [2*B] {gain, loss}, pre-zeroed
{
    __shared__ float ys[MB][S_];
    __shared__ float red[4][MB][2];

    const int bg = blockIdx.x / GC;
    const int c  = blockIdx.x % GC;
    const int b0 = bg * MB;
    const int tid = threadIdx.x;

    #pragma unroll
    for (int mb = 0; mb < MB; ++mb)
        for (int i = tid; i < S_; i += TPB) ys[mb][i] = y[(b0 + mb) * S_ + i];
    __syncthreads();

    float lt2[MB], nivt[MB], den[MB];
    #pragma unroll
    for (int mb = 0; mb < MB; ++mb) {
        float T  = T_gas[b0 + mb];
        den[mb]  = den_gas[b0 + mb];
        lt2[mb]  = log2f(T * (1.0f / 300.0f));
        nivt[mb] = -LOG2E_ / T;
    }

    float gain[MB] = {0, 0, 0, 0}, loss[MB] = {0, 0, 0, 0};

    {   // 1st-order, 625 edges per chunk each
        const int n = E1G_ / GC, e0 = c * n, e1 = e0 + n;
        for (int e = e0 + tid; e < e1; e += TPB) red1_gl(g1[e], ys, lt2, nivt, gain);
        for (int e = e0 + tid; e < e1; e += TPB) red1_gl(l1[e], ys, lt2, nivt, loss);
    }
    {   // 2nd-order gain, 1875 per chunk, unroll 2
        const int n = E2G_ / GC, e0 = c * n, e1 = e0 + n;
        int e = e0 + tid;
        for (; e + TPB < e1; e += 2 * TPB) {
            float4 q0 = g2[e], q1 = g2[e + TPB];
            red2_gl(q0, ys, lt2, nivt, den, gain);
            red2_gl(q1, ys, lt2, nivt, den, gain);
        }
        for (; e < e1; e += TPB) red2_gl(g2[e], ys, lt2, nivt, den, gain);
    }
    {   // 2nd-order loss
        const int n = E2L_ / GC, e0 = c * n, e1 = e0 + n;
        int e = e0 + tid;
        for (; e + TPB < e1; e += 2 * TPB) {
            float4 q0 = l2[e], q1 = l2[e + TPB];
            red2_gl(q0, ys, lt2, nivt, den, loss);
            red2_gl(q1, ys, lt2, nivt, den, loss);
        }
        for (; e < e1; e += TPB) red2_gl(l2[e], ys, lt2, nivt, den, loss);
    }

    const int lane = tid & 63, wid = tid >> 6;
    #pragma unroll
    for (int mb = 0; mb < MB; ++mb) {
        float g = gain[mb], l = loss[mb];
        #pragma unroll
        for (int o = 32; o > 0; o >>= 1) {
            g += __shfl_down(g, o, 64);
            l += __shfl_down(l, o, 64);
        }
        if (lane == 0) { red[wid][mb][0] = g; red[wid][mb][1] = l; }
    }
    __syncthreads();
    if (tid < 2 * MB) {
        int mb = tid >> 1, gl = tid & 1;
        float v = red[0][mb][gl] + red[1][mb][gl] + red[2][mb][gl] + red[3][mb][gl];
        atomicAdd(&part[2 * (b0 + mb) + gl], v);
    }
}

// ---------------------------------------------------------------------------
// K2: final RHS via sorted-gather.  grid = NBG*PC.
// Block: MB=4 batches x PPB=16 products; wave wid owns PPW=4 products,
// lanes stride each product's contiguous edge run, shuffle-reduce, store.
// ---------------------------------------------------------------------------
__global__ __launch_bounds__(TPB, 6) void final_gather_kernel(
    const float* __restrict__ y, const float* __restrict__ den_gas,
    const float* __restrict__ T_gas,
    const float4* __restrict__ sorted, const int* __restrict__ starts,
    const float* __restrict__ part,
    float* __restrict__ out)
{
    __shared__ float ys[MB][S_];
    __shared__ float w[MB][WW];       // [0..799]=ys*den, 800=1, 801=ks, 802=km

    const int bg = blockIdx.x / PC;
    const int pc = blockIdx.x % PC;
    const int b0 = bg * MB;
    const int tid = threadIdx.x, lane = tid & 63, wid = tid >> 6;

    #pragma unroll
    for (int mb = 0; mb < MB; ++mb)
        for (int i = tid; i < S_; i += TPB) ys[mb][i] = y[(b0 + mb) * S_ + i];
    __syncthreads();

    // wave `wid` derives k_s2m/k_m2s for batch b0+wid into w[wid][801..802]
    {
        const int mb = wid;
        float vs = 0.f, vm = 0.f;
        for (int i = lane; i < 300; i += 64) { vs += ys[mb][200 + i]; vm += ys[mb][500 + i]; }
        #pragma unroll
        for (int o = 32; o > 0; o >>= 1) {
            vs += __shfl_down(vs, o, 64);
            vm += __shfl_down(vm, o, 64);
        }
        if (lane == 0) {
            float gain = part[2 * (b0 + mb) + 0], loss = part[2 * (b0 + mb) + 1];
            float n_layer = 1e-2f * (vs + vm);
            float decay = fminf(2.0f / fmaxf(n_layer, EPS_), 1.0f);
            w[mb][IB_ONE] = 1.0f;
            w[mb][IB_KS]  = gain / fmaxf(vs, EPS_);
            w[mb][IB_KM]  = loss / fmaxf(vm, EPS_) * decay;
            w[mb][IB_KM + 1] = 0.0f;
        }
    }

    float lt2[MB], nivt[MB], den[MB];
    #pragma unroll
    for (int mb = 0; mb < MB; ++mb) {
        float T  = T_gas[b0 + mb];
        den[mb]  = den_gas[b0 + mb];
        lt2[mb]  = log2f(T * (1.0f / 300.0f));
        nivt[mb] = -LOG2E_ / T;
    }
    #pragma unroll
    for (int mb = 0; mb < MB; ++mb)
        for (int i = tid; i < S_; i += TPB) w[mb][i] = ys[mb][i] * den[mb];
    __syncthreads();

    const int pbase = pc * PPB + wid * PPW;
    for (int pi = 0; pi < PPW; ++pi) {
        const int p  = pbase + pi;
        const int s0 = starts[p], s1 = starts[p + 1];
        float acc[MB] = {0.f, 0.f, 0.f, 0.f};
        int e = s0 + lane;
        // 2x unrolled: two 16B loads in flight
        for (; e + 64 < s1; e += 128) {
            float4 q0 = sorted[e];
            float4 q1 = sorted[e + 64];
            int b0s = __float_as_int(q0.w);
            int b1s = __float_as_int(q1.w);
            int ia0 = b0s & 1023, ib0 = (b0s >> 10) & 1023;
            int ia1 = b1s & 1023, ib1 = (b1s >> 10) & 1023;
            #pragma unroll
            for (int mb = 0; mb < MB; ++mb) {
                float e0 = exp2f(fmaf(q0.y, lt2[mb], q0.z * nivt[mb]));
                float e1 = exp2f(fmaf(q1.y, lt2[mb], q1.z * nivt[mb]));
                acc[mb] += q0.x * e0 * ys[mb][ia0] * w[mb][ib0]
                         + q1.x * e1 * ys[mb][ia1] * w[mb][ib1];
            }
        }
        if (e < s1) {
            float4 q = sorted[e];
            int bs = __float_as_int(q.w);
            int ia = bs & 1023, ib = (bs >> 10) & 1023;
            #pragma unroll
            for (int mb = 0; mb < MB; ++mb) {
                float ee = exp2f(fmaf(q.y, lt2[mb], q.z * nivt[mb]));
                acc[mb] += q.x * ee * ys[mb][ia] * w[mb][ib];
            }
        }
        #pragma unroll
        for (int mb = 0; mb < MB; ++mb) {
            float v = acc[mb];
            #pragma unroll
            for (int o = 32; o > 0; o >>= 1) v += __shfl_down(v, o, 64);
            if (lane == 0) out[(b0 + mb) * S_ + p] = v;   // direct store, no atomic
        }
    }
}

// ---------------------------------------------------------------------------
extern "C" void kernel_launch(void* const* d_in, const int* in_sizes, int n_in,
                              void* d_out, int out_size, void* d_ws, size_t ws_size,
                              hipStream_t stream) {
    const float* y       = (const float*)d_in[1];
    const float* den_gas = (const float*)d_in[2];
    const float* T_gas   = (const float*)d_in[3];
    const float* alpha   = (const float*)d_in[4];
    const float* beta    = (const float*)d_in[5];
    const float* gam     = (const float*)d_in[6];
    const int* k1  = (const int*)d_in[7];
    const int* r1  = (const int*)d_in[8];
    const int* p1  = (const int*)d_in[9];
    const int* s1  = (const int*)d_in[10];
    const int* k2  = (const int*)d_in[11];
    const int* ra2 = (const int*)d_in[12];
    const int* rb2 = (const int*)d_in[13];
    const int* p2  = (const int*)d_in[14];
    const int* s2  = (const int*)d_in[15];
    const int* k1g  = (const int*)d_in[16];
    const int* r1g  = (const int*)d_in[17];
    const int* p1g  = (const int*)d_in[18];
    const int* s1g  = (const int*)d_in[19];
    const int* k2g  = (const int*)d_in[20];
    const int* ra2g = (const int*)d_in[21];
    const int* rb2g = (const int*)d_in[22];
    const int* p2g  = (const int*)d_in[23];
    const int* s2g  = (const int*)d_in[24];
    const int* k1l  = (const int*)d_in[25];
    const int* r1l  = (const int*)d_in[26];
    const int* p1l  = (const int*)d_in[27];
    const int* s1l  = (const int*)d_in[28];
    const int* k2l  = (const int*)d_in[29];
    const int* ra2l = (const int*)d_in[30];
    const int* rb2l = (const int*)d_in[31];
    const int* p2l  = (const int*)d_in[32];
    const int* s2l  = (const int*)d_in[33];

    // workspace layout
    char* wsp = (char*)d_ws;
    size_t off = 0;
    float4* sorted = (float4*)(wsp + off); off += (size_t)ET_  * 16;
    float4* g1 = (float4*)(wsp + off); off += (size_t)E1G_ * 16;
    float4* g2 = (float4*)(wsp + off); off += (size_t)E2G_ * 16;
    float4* l1 = (float4*)(wsp + off); off += (size_t)E1L_ * 16;
    float4* l2 = (float4*)(wsp + off); off += (size_t)E2L_ * 16;
    int* cnt    = (int*)(wsp + off); off += (size_t)S_ * PAD * 4;
    int* rank   = (int*)(wsp + off); off += (size_t)S_ * PAD * 4;
    int* starts = (int*)(wsp + off); off += (size_t)(S_ + 1) * 4;
    float* part = (float*)(wsp + off); off += (size_t)2 * B_ * 4;

    float* out = (float*)d_out;

    hipMemsetAsync(cnt,  0, (size_t)S_ * PAD * 4, stream);
    hipMemsetAsync(part, 0, (size_t)2 * B_ * sizeof(float), stream);

    // counting sort of final edges by product p (batch-independent)
    hist_kernel<<<(ET_ + 255) / 256, 256, 0, stream>>>(p1, p2, cnt);
    scan_kernel<<<1, 1024, 0, stream>>>(cnt, starts, rank);
    reorder1_kernel<<<(E1_ + 255) / 256, 256, 0, stream>>>(
        alpha, beta, gam, k1, r1, p1, s1, rank, sorted);
    reorder2_kernel<<<(E2_ + 255) / 256, 256, 0, stream>>>(
        alpha, beta, gam, k2, ra2, rb2, p2, s2, rank, sorted);

    // gain/loss packed streams
    pack1gl_kernel<<<(E1G_ + 255) / 256, 256, 0, stream>>>(E1G_, alpha, beta, gam, k1g, r1g, p1g, s1g, g1);
    pack2gl_kernel<<<(E2G_ + 255) / 256, 256, 0, stream>>>(E2G_, alpha, beta, gam, k2g, ra2g, rb2g, p2g, s2g, g2);
    pack1gl_kernel<<<(E1L_ + 255) / 256, 256, 0, stream>>>(E1L_, alpha, beta, gam, k1l, r1l, p1l, s1l, l1);
    pack2gl_kernel<<<(E2L_ + 255) / 256, 256, 0, stream>>>(E2L_, alpha, beta, gam, k2l, ra2l, rb2l, p2l, s2l, l2);

    // K1: gain/loss partial sums
    gainloss_kernel<<<NBG * GC, TPB, 0, stream>>>(y, den_gas, T_gas, g1, g2, l1, l2, part);

    // K2: final assembly by gather (no atomics; fully covers d_out)
    final_gather_kernel<<<NBG * PC, TPB, 0, stream>>>(
        y, den_gas, T_gas, sorted, starts, part, out);
}